// Round 3
// baseline (32.644 us; speedup 1.0000x reference)
//
#include <hip/hip_runtime.h>
#include <math.h>

#define L_SEQ 4096   // sequence length L
#define NT 256       // threads per block (one block per sequence)
#define CHUNK 16     // L_SEQ / NT elements per thread
#define NW (NT/64)   // waves per block (4)

struct M2 { float a00, a01, a10, a11; };

// max-plus 2x2 compose: C[s][t] = max_k(A[s][k] + B[k][t])
__device__ __forceinline__ M2 mpc(const M2& A, const M2& B) {
  M2 C;
  C.a00 = fmaxf(A.a00 + B.a00, A.a01 + B.a10);
  C.a01 = fmaxf(A.a00 + B.a01, A.a01 + B.a11);
  C.a10 = fmaxf(A.a10 + B.a00, A.a11 + B.a10);
  C.a11 = fmaxf(A.a10 + B.a01, A.a11 + B.a11);
  return C;
}

__device__ __forceinline__ M2 ldm(const float4& v) { return M2{v.x, v.y, v.z, v.w}; }
__device__ __forceinline__ float4 stm(const M2& m) { return make_float4(m.a00, m.a01, m.a10, m.a11); }

__global__ __launch_bounds__(NT, 4) void chain_fb_kernel(
    const float* __restrict__ jp, const float* __restrict__ bp,
    const int* __restrict__ obs, float* __restrict__ out) {
  __shared__ float4 T4s[16];    // 4-element-pattern transforms
  __shared__ float4 T8s[256];   // 8-element-pattern transforms (4 KB)
  __shared__ float4 wtf[NW];    // forward wave totals
  __shared__ float4 wtb[NW];    // backward wave totals

  const int t = threadIdx.x;
  const int lane = t & 63;
  const int w = t >> 6;
  const long b = blockIdx.x;

  const float P   = 0.25f * jp[0];   // psi = [[P,-P],[-P,P]]
  const float hb0 = 0.5f * bp[0];    // u_i = 0.5*b[obs_i]; phi_i = (-u, +u)
  const float hb1 = 0.5f * bp[1];

  // ---- load this thread's 16 obs (contiguous 64B, coalesced), pack bit mask
  const int4* rowp = (const int4*)(obs + b * L_SEQ + (long)t * CHUNK);
  int4 q0 = rowp[0], q1 = rowp[1], q2 = rowp[2], q3 = rowp[3];
  int ov[CHUNK] = {q0.x, q0.y, q0.z, q0.w, q1.x, q1.y, q1.z, q1.w,
                   q2.x, q2.y, q2.z, q2.w, q3.x, q3.y, q3.z, q3.w};
  unsigned m = 0;
  #pragma unroll
  for (int e = 0; e < CHUNK; ++e) m |= (unsigned)(ov[e] & 1) << e;

  // ---- build LUT: T4s[p] = E(p&1)(*)E(p>>1&1)(*)E(p>>2&1)(*)E(p>>3&1)
  //      (bit 0 = earliest element);  E(u) = [[P-u, -u-P],[u-P, u+P]]
  if (t < 16) {
    float u0 = (t & 1) ? hb1 : hb0;
    M2 Tt{P - u0, -u0 - P, u0 - P, u0 + P};
    #pragma unroll
    for (int k = 1; k < 4; ++k) {
      float uk = ((t >> k) & 1) ? hb1 : hb0;
      M2 Ek{P - uk, -uk - P, uk - P, uk + P};
      Tt = mpc(Tt, Ek);
    }
    T4s[t] = stm(Tt);
  }
  __syncthreads();
  T8s[t] = stm(mpc(ldm(T4s[t & 15]), ldm(T4s[(t >> 4) & 15])));
  __syncthreads();

  // ---- chunk transforms by table lookup
  unsigned r16 = __brev(m) >> 16;   // 16-bit bit-reversal: bwd element order
  M2 T = mpc(ldm(T8s[m & 255]),   ldm(T8s[(m >> 8) & 255]));    // fwd
  M2 R = mpc(ldm(T8s[r16 & 255]), ldm(T8s[(r16 >> 8) & 255]));  // bwd

  // ---- fused Hillis-Steele scans: prefix (shfl_up) + suffix (shfl_down)
  #pragma unroll
  for (int off = 1; off < 64; off <<= 1) {
    M2 OF{__shfl_up(T.a00, off), __shfl_up(T.a01, off),
          __shfl_up(T.a10, off), __shfl_up(T.a11, off)};
    M2 OB{__shfl_down(R.a00, off), __shfl_down(R.a01, off),
          __shfl_down(R.a10, off), __shfl_down(R.a11, off)};
    if (lane >= off)      T = mpc(OF, T);   // earlier-in-order on the left
    if (lane < 64 - off)  R = mpc(OB, R);   // higher-index on the left
  }
  if (lane == 63) wtf[w] = stm(T);
  if (lane == 0)  wtb[w] = stm(R);

  // intra-wave exclusive versions
  M2 EF{__shfl_up(T.a00, 1), __shfl_up(T.a01, 1),
        __shfl_up(T.a10, 1), __shfl_up(T.a11, 1)};
  M2 EB{__shfl_down(R.a00, 1), __shfl_down(R.a01, 1),
        __shfl_down(R.a10, 1), __shfl_down(R.a11, 1)};
  if (lane == 0)  { EF.a00 = 0.f; EF.a01 = -INFINITY; EF.a10 = -INFINITY; EF.a11 = 0.f; }
  if (lane == 63) { EB.a00 = 0.f; EB.a01 = -INFINITY; EB.a10 = -INFINITY; EB.a11 = 0.f; }

  __syncthreads();  // wave totals visible

  M2 GF = EF, GB = EB;
  for (int ww = w - 1; ww >= 0; --ww) GF = mpc(ldm(wtf[ww]), GF);
  for (int ww = w + 1; ww < NW; ++ww) GB = mpc(ldm(wtb[ww]), GB);
  // apply zero init vector: m[t] = max_s G[s][t]
  float fm0 = fmaxf(GF.a00, GF.a10), fm1 = fmaxf(GF.a01, GF.a11);
  float bm0 = fmaxf(GB.a00, GB.a10), bm1 = fmaxf(GB.a01, GB.a11);

  // ---- fwd replay: o = phi + fwd  (x,y are exactly phi+msg)
  float o0[CHUNK], o1[CHUNK];
  #pragma unroll
  for (int e = 0; e < CHUNK; ++e) {
    float u = ((m >> e) & 1) ? hb1 : hb0;
    float x = fm0 - u, y = fm1 + u;
    o0[e] = x; o1[e] = y;
    fm0 = fmaxf(x + P, y - P);
    fm1 = fmaxf(x - P, y + P);
  }
  // ---- bwd replay: add bwd message (right->left)
  #pragma unroll
  for (int e = CHUNK - 1; e >= 0; --e) {
    float u = ((m >> e) & 1) ? hb1 : hb0;
    o0[e] += bm0; o1[e] += bm1;
    float x = bm0 - u, y = bm1 + u;
    bm0 = fmaxf(x + P, y - P);
    bm1 = fmaxf(x - P, y + P);
  }

  // ---- store: contiguous 16 floats per state row (coalesced float4s)
  const long base = (long)t * CHUNK;
  float* r0 = out + b * (2L * L_SEQ) + base;   // out[b][0][base..]
  float* r1 = r0 + L_SEQ;                      // out[b][1][base..]
  #pragma unroll
  for (int v = 0; v < CHUNK / 4; ++v) {
    ((float4*)r0)[v] = make_float4(o0[4*v], o0[4*v+1], o0[4*v+2], o0[4*v+3]);
    ((float4*)r1)[v] = make_float4(o1[4*v], o1[4*v+1], o1[4*v+2], o1[4*v+3]);
  }
}

extern "C" void kernel_launch(void* const* d_in, const int* in_sizes, int n_in,
                              void* d_out, int out_size, void* d_ws, size_t ws_size,
                              hipStream_t stream) {
  const float* jp  = (const float*)d_in[0];
  const float* bp  = (const float*)d_in[1];
  const int*   obs = (const int*)d_in[2];
  float* out = (float*)d_out;
  const int B = in_sizes[2] / L_SEQ;   // 2048
  chain_fb_kernel<<<B, NT, 0, stream>>>(jp, bp, obs, out);
}

// Round 4
// 25.375 us; speedup vs baseline: 1.2864x; 1.2864x over previous
//
#include <hip/hip_runtime.h>
#include <math.h>

#define L_SEQ 4096   // sequence length L
#define NT 512       // threads per block (one block per sequence)
#define CHUNK 8      // L_SEQ / NT elements per thread
#define NW (NT/64)   // waves per block (8)

struct M2 { float a00, a01, a10, a11; };

// max-plus 2x2 compose: C[s][t] = max_k(A[s][k] + B[k][t])
__device__ __forceinline__ M2 mpc(const M2& A, const M2& B) {
  M2 C;
  C.a00 = fmaxf(A.a00 + B.a00, A.a01 + B.a10);
  C.a01 = fmaxf(A.a00 + B.a01, A.a01 + B.a11);
  C.a10 = fmaxf(A.a10 + B.a00, A.a11 + B.a10);
  C.a11 = fmaxf(A.a10 + B.a01, A.a11 + B.a11);
  return C;
}

__device__ __forceinline__ M2 ldm(const float4& v) { return M2{v.x, v.y, v.z, v.w}; }
__device__ __forceinline__ float4 stm(const M2& m) { return make_float4(m.a00, m.a01, m.a10, m.a11); }

__global__ __launch_bounds__(NT, 8) void chain_fb_kernel(
    const float* __restrict__ jp, const float* __restrict__ bp,
    const int* __restrict__ obs, float* __restrict__ out) {
  __shared__ float4 T4s[16];                      // 4-bit-pattern transforms
  __shared__ float T8a[256], T8b[256], T8c[256], T8d[256];  // 8-bit LUT, SoA (4 KB)
  __shared__ float4 wtf[NW];   // forward wave totals
  __shared__ float4 wtb[NW];   // backward wave totals

  const int t = threadIdx.x;
  const int lane = t & 63;
  const int w = t >> 6;
  const long b = blockIdx.x;

  const float P   = 0.25f * jp[0];   // psi = [[P,-P],[-P,P]]
  const float hb0 = 0.5f * bp[0];    // u_i = 0.5*b[obs_i]; phi_i = (-u, +u)
  const float hb1 = 0.5f * bp[1];

  // ---- issue obs load first (global latency overlaps LUT build)
  const int4* rowp = (const int4*)(obs + b * L_SEQ + (long)t * CHUNK);
  int4 q0 = rowp[0], q1 = rowp[1];

  // ---- build LUT: pattern p -> E(p0)(*)E(p1)(*)...  (bit 0 = earliest elem)
  //      E(u) = [[P-u, -u-P],[u-P, u+P]]
  if (t < 16) {
    float u0 = (t & 1) ? hb1 : hb0;
    M2 Tt{P - u0, -u0 - P, u0 - P, u0 + P};
    #pragma unroll
    for (int k = 1; k < 4; ++k) {
      float uk = ((t >> k) & 1) ? hb1 : hb0;
      M2 Ek{P - uk, -uk - P, uk - P, uk + P};
      Tt = mpc(Tt, Ek);
    }
    T4s[t] = stm(Tt);
  }
  __syncthreads();
  if (t < 256) {
    M2 M = mpc(ldm(T4s[t & 15]), ldm(T4s[(t >> 4) & 15]));
    T8a[t] = M.a00; T8b[t] = M.a01; T8c[t] = M.a10; T8d[t] = M.a11;
  }

  // pack obs bit mask while the barrier drains
  unsigned m = (unsigned)(q0.x & 1)       | (unsigned)(q0.y & 1) << 1 |
               (unsigned)(q0.z & 1) << 2  | (unsigned)(q0.w & 1) << 3 |
               (unsigned)(q1.x & 1) << 4  | (unsigned)(q1.y & 1) << 5 |
               (unsigned)(q1.z & 1) << 6  | (unsigned)(q1.w & 1) << 7;
  __syncthreads();

  // ---- chunk transforms: pure lookups (bwd = bit-reversed pattern)
  const unsigned r = __brev(m) >> 24;
  M2 T{T8a[m], T8b[m], T8c[m], T8d[m]};   // fwd: E(u0)(*)...(*)E(u7)
  M2 R{T8a[r], T8b[r], T8c[r], T8d[r]};   // bwd: E(u7)(*)...(*)E(u0)

  // ---- fused Hillis-Steele scans: prefix (shfl_up) + suffix (shfl_down)
  #pragma unroll
  for (int off = 1; off < 64; off <<= 1) {
    M2 OF{__shfl_up(T.a00, off), __shfl_up(T.a01, off),
          __shfl_up(T.a10, off), __shfl_up(T.a11, off)};
    M2 OB{__shfl_down(R.a00, off), __shfl_down(R.a01, off),
          __shfl_down(R.a10, off), __shfl_down(R.a11, off)};
    if (lane >= off)      T = mpc(OF, T);   // earlier-in-order on the left
    if (lane < 64 - off)  R = mpc(OB, R);   // higher-index on the left
  }
  if (lane == 63) wtf[w] = stm(T);
  if (lane == 0)  wtb[w] = stm(R);

  // intra-wave exclusive versions
  M2 EF{__shfl_up(T.a00, 1), __shfl_up(T.a01, 1),
        __shfl_up(T.a10, 1), __shfl_up(T.a11, 1)};
  M2 EB{__shfl_down(R.a00, 1), __shfl_down(R.a01, 1),
        __shfl_down(R.a10, 1), __shfl_down(R.a11, 1)};
  if (lane == 0)  { EF.a00 = 0.f; EF.a01 = -INFINITY; EF.a10 = -INFINITY; EF.a11 = 0.f; }
  if (lane == 63) { EB.a00 = 0.f; EB.a01 = -INFINITY; EB.a10 = -INFINITY; EB.a11 = 0.f; }

  __syncthreads();  // wave totals visible

  M2 GF = EF, GB = EB;
  for (int ww = w - 1; ww >= 0; --ww) GF = mpc(ldm(wtf[ww]), GF);
  for (int ww = w + 1; ww < NW; ++ww) GB = mpc(ldm(wtb[ww]), GB);
  // apply zero init vector: msg[t] = max_s G[s][t]
  float fm0 = fmaxf(GF.a00, GF.a10), fm1 = fmaxf(GF.a01, GF.a11);
  float bm0 = fmaxf(GB.a00, GB.a10), bm1 = fmaxf(GB.a01, GB.a11);

  // ---- fwd replay: o = phi + fwd  (x,y are exactly phi+msg)
  float o0[CHUNK], o1[CHUNK];
  #pragma unroll
  for (int e = 0; e < CHUNK; ++e) {
    float u = ((m >> e) & 1) ? hb1 : hb0;
    float x = fm0 - u, y = fm1 + u;
    o0[e] = x; o1[e] = y;
    fm0 = fmaxf(x + P, y - P);
    fm1 = fmaxf(x - P, y + P);
  }
  // ---- bwd replay: add bwd message (right->left)
  #pragma unroll
  for (int e = CHUNK - 1; e >= 0; --e) {
    float u = ((m >> e) & 1) ? hb1 : hb0;
    o0[e] += bm0; o1[e] += bm1;
    float x = bm0 - u, y = bm1 + u;
    bm0 = fmaxf(x + P, y - P);
    bm1 = fmaxf(x - P, y + P);
  }

  // ---- store: contiguous 8 floats per state row (coalesced float4s)
  const long base = (long)t * CHUNK;
  float* r0 = out + b * (2L * L_SEQ) + base;   // out[b][0][base..]
  float* r1 = r0 + L_SEQ;                      // out[b][1][base..]
  ((float4*)r0)[0] = make_float4(o0[0], o0[1], o0[2], o0[3]);
  ((float4*)r0)[1] = make_float4(o0[4], o0[5], o0[6], o0[7]);
  ((float4*)r1)[0] = make_float4(o1[0], o1[1], o1[2], o1[3]);
  ((float4*)r1)[1] = make_float4(o1[4], o1[5], o1[6], o1[7]);
}

extern "C" void kernel_launch(void* const* d_in, const int* in_sizes, int n_in,
                              void* d_out, int out_size, void* d_ws, size_t ws_size,
                              hipStream_t stream) {
  const float* jp  = (const float*)d_in[0];
  const float* bp  = (const float*)d_in[1];
  const int*   obs = (const int*)d_in[2];
  float* out = (float*)d_out;
  const int B = in_sizes[2] / L_SEQ;   // 2048
  chain_fb_kernel<<<B, NT, 0, stream>>>(jp, bp, obs, out);
}